// Round 21
// baseline (64.628 us; speedup 1.0000x reference)
//
#include <hip/hip_runtime.h>
#include <math.h>

// critic_attention, round 21: r20 champion (61.0us) -> 4-wave blocks.
// r20 evidence: VALUBusy 30%, occupancy 37.6% at VGPR 64 -> SIMDs idle on the
// per-agent serial chain with only ~3 resident waves/SIMD; grid shape (4096
// blocks x 2 waves) is the residency limiter, not registers.
// Fix: block = 4 waves on ONE 16-item tile. Wave w: agent 0 (a_self, cheap
// redundancy) + agents {1+4w..4+4w} (w3: 3 agents). 16384 waves = 2x
// oversubscription; per-wave phase A 9 -> ~5 agent bodies. Merge = same
// associative no-max softmax, 3 partial LDS buffers + wave0 combine.
// Phase B: wave w owns cols [32w, 32w+32) (half the MFMAs/wave of r20).
// All numerics identical to r20 (absmax must stay 4.88e-4).
//
// Fragment conventions (m89-verified, rounds 6-20):
//   A-frag: lane row (l&15)=item, k=(l>>4)*8+e ; B-frag: lane col, same k
//   D: lane col (l&15), row=(l>>4)*4+reg = item
// ws layout (halfs): W0h@0[2][4][4][16][8] W0l@4096(unused) |
//   W2h@8192[4][8][4][16][8] W2l@24576 | W3h@40960 W3l@57344.

#define SLOPE 0.01f
#define LOG2E 1.4426950408889634f

typedef _Float16 f16x8 __attribute__((ext_vector_type(8)));
typedef _Float16 f16x2 __attribute__((ext_vector_type(2)));
typedef float f32x4 __attribute__((ext_vector_type(4)));

#define MFMA(a, b, c) __builtin_amdgcn_mfma_f32_16x16x32_f16((a), (b), (c), 0, 0, 0)

__device__ __forceinline__ float lrelu(float x) { return fmaxf(x, SLOPE * x); }

// tanh(x) = 1 - 2/(e^{2x}+1), raw v_exp_f32 + v_rcp_f32
__device__ __forceinline__ float fast_tanh(float x) {
    float e = __builtin_amdgcn_exp2f(x * (2.0f * LOG2E));
    float r = __builtin_amdgcn_rcpf(e + 1.0f);
    return fmaf(-2.0f, r, 1.0f);
}

// 8x f32 -> f16x8 via 4x v_cvt_pkrtz_f16_f32 (packed output = MFMA layout)
__device__ __forceinline__ f16x8 cvt8(const float f[8]) {
    f16x2 a = __builtin_bit_cast(f16x2, __builtin_amdgcn_cvt_pkrtz(f[0], f[1]));
    f16x2 b = __builtin_bit_cast(f16x2, __builtin_amdgcn_cvt_pkrtz(f[2], f[3]));
    f16x2 c = __builtin_bit_cast(f16x2, __builtin_amdgcn_cvt_pkrtz(f[4], f[5]));
    f16x2 d = __builtin_bit_cast(f16x2, __builtin_amdgcn_cvt_pkrtz(f[6], f[7]));
    f16x8 r;
    r[0] = a[0]; r[1] = a[1]; r[2] = b[0]; r[3] = b[1];
    r[4] = c[0]; r[5] = c[1]; r[6] = d[0]; r[7] = d[1];
    return r;
}

// all-lanes sum within each 16-lane row: 4x v_add with DPP row_ror (VALU pipe)
__device__ __forceinline__ float rowsum16(float x) {
    int t;
    t = __builtin_amdgcn_update_dpp(0, __builtin_bit_cast(int, x), 0x121, 0xf, 0xf, true);
    x += __builtin_bit_cast(float, t);
    t = __builtin_amdgcn_update_dpp(0, __builtin_bit_cast(int, x), 0x122, 0xf, 0xf, true);
    x += __builtin_bit_cast(float, t);
    t = __builtin_amdgcn_update_dpp(0, __builtin_bit_cast(int, x), 0x124, 0xf, 0xf, true);
    x += __builtin_bit_cast(float, t);
    t = __builtin_amdgcn_update_dpp(0, __builtin_bit_cast(int, x), 0x128, 0xf, 0xf, true);
    x += __builtin_bit_cast(float, t);
    return x;
}

// ---------------- prep: split weights into per-lane fp16 hi/lo fragments ----------------
__global__ __launch_bounds__(256) void pack_weights(
    const float* __restrict__ W0, const float* __restrict__ W2,
    const float* __restrict__ W3, _Float16* __restrict__ ws)
{
    const int g = blockIdx.x * 256 + threadIdx.x;
    if (g >= 4608) return;

    const float* src;
    int ks, ct, lg, lr, ncol, kmax;
    long hoff, loff;
    if (g < 512) {                       // W0: [2][4][4][16]
        ks = g >> 8; ct = (g >> 6) & 3; lg = (g >> 4) & 3; lr = g & 15;
        src = W0; ncol = 64; kmax = 40;
        hoff = (long)g * 8;  loff = hoff + 4096;
    } else if (g < 2560) {               // W2: [4][8][4][16]
        int gg = g - 512;
        ks = gg >> 9; ct = (gg >> 6) & 7; lg = (gg >> 4) & 3; lr = gg & 15;
        src = W2; ncol = 128; kmax = 128;
        hoff = 8192 + (long)gg * 8; loff = hoff + 16384;
    } else {                             // W3: [4][8][4][16]
        int gg = g - 2560;
        ks = gg >> 9; ct = (gg >> 6) & 7; lg = (gg >> 4) & 3; lr = gg & 15;
        src = W3; ncol = 128; kmax = 128;
        hoff = 40960 + (long)gg * 8; loff = hoff + 16384;
    }

    f16x8 hi, lo;
#pragma unroll
    for (int e = 0; e < 8; ++e) {
        const int k = ks * 32 + lg * 8 + e;
        const float v = (k < kmax) ? src[(long)k * ncol + ct * 16 + lr] : 0.f;
        _Float16 h = (_Float16)v;
        hi[e] = h;
        lo[e] = (_Float16)(v - (float)h);
    }
    *reinterpret_cast<f16x8*>(ws + hoff) = hi;
    *reinterpret_cast<f16x8*>(ws + loff) = lo;
}

__global__ __launch_bounds__(256, 2) void critic_attention_kernel(
    const float* __restrict__ obs, const float* __restrict__ act,
    const float* __restrict__ b0, const float* __restrict__ W1,
    const float* __restrict__ b1v, const float* __restrict__ b2,
    const float* __restrict__ b3, const float* __restrict__ Wc,
    const float* __restrict__ bcv, const _Float16* __restrict__ ws,
    float* __restrict__ out)
{
    __shared__ __align__(16) _Float16 xcat[16 * 136]; // x_cat/x1 fp16
    __shared__ float part[3][16 * 68]; // waves 1-3 partial xsum (fp32)
    __shared__ float ps[3][16];        // waves 1-3 partial s
    __shared__ float vpart[4][16];     // Wc partials per wave

    const int t = threadIdx.x;
    const int lane = t & 63;
    const int w = t >> 6;              // wave 0..3
    const int lr = lane & 15;          // A-row (item) / D-col
    const int lg = lane >> 4;          // k-chunk / D-row-group

    const long ibase = (long)blockIdx.x * 16;

    // W0 HI fragments only
    f16x8 w0h[2][4];
#pragma unroll
    for (int ks = 0; ks < 2; ++ks)
#pragma unroll
        for (int ct = 0; ct < 4; ++ct) {
            const long o = (((long)(ks * 4 + ct) * 4 + lg) * 16 + lr) * 8;
            w0h[ks][ct] = *reinterpret_cast<const f16x8*>(ws + o);
        }

    float b0c[4], W1sc[4], W1oc[4];
#pragma unroll
    for (int ct = 0; ct < 4; ++ct) {
        b0c[ct]  = b0[ct * 16 + lr];
        W1sc[ct] = W1[ct * 16 + lr];
        W1oc[ct] = W1[64 + ct * 16 + lr];
    }
    const float b1s = b1v[0];

    const float* obase = obs + (ibase + lr) * 512 + lg * 8;   // this lane's item row
    const float* abase = act + (ibase + lr) * 128;            // lg==0 lanes only

    const int abeg = 1 + 4 * w;                 // w0:1-4 w1:5-8 w2:9-12 w3:13-15
    const int aend = (w == 3) ? 16 : abeg + 4;

    float4 q0 = *reinterpret_cast<const float4*>(obase);
    float4 q1 = *reinterpret_cast<const float4*>(obase + 4);
    float4 c0 = make_float4(0.f, 0.f, 0.f, 0.f), c1 = c0;
    if (lg == 0) {
        c0 = *reinterpret_cast<const float4*>(abase);
        c1 = *reinterpret_cast<const float4*>(abase + 4);
    }

    // ---------------- agent 0: all waves (only a_self needed; w0 stores x_self) ----------------
    float a_self[4], s[4], xsum[4][4];
    {
        float f0[8] = {q0.x, q0.y, q0.z, q0.w, q1.x, q1.y, q1.z, q1.w};
        float f1[8] = {c0.x, c0.y, c0.z, c0.w, c1.x, c1.y, c1.z, c1.w};
        f16x8 bi0 = cvt8(f0);
        f16x8 bi1 = cvt8(f1);

        // prefetch this wave's first loop agent
        q0 = *reinterpret_cast<const float4*>(obase + abeg * 32);
        q1 = *reinterpret_cast<const float4*>(obase + abeg * 32 + 4);
        if (lg == 0) {
            c0 = *reinterpret_cast<const float4*>(abase + abeg * 8);
            c1 = *reinterpret_cast<const float4*>(abase + abeg * 8 + 4);
        }

        f32x4 acc[4];
#pragma unroll
        for (int ct = 0; ct < 4; ++ct) {
            acc[ct] = (f32x4){b0c[ct], b0c[ct], b0c[ct], b0c[ct]};  // bias folded
            acc[ct] = MFMA(bi0, w0h[0][ct], acc[ct]);
            acc[ct] = MFMA(bi1, w0h[1][ct], acc[ct]);
        }

        float xa[4][4], p[4];
#pragma unroll
        for (int j = 0; j < 4; ++j) {
#pragma unroll
            for (int ct = 0; ct < 4; ++ct)
                xa[ct][j] = lrelu(acc[ct][j]);
            p[j] = xa[0][j] * W1sc[0];
            p[j] = fmaf(xa[1][j], W1sc[1], p[j]);
            p[j] = fmaf(xa[2][j], W1sc[2], p[j]);
            p[j] = fmaf(xa[3][j], W1sc[3], p[j]);
            p[j] = rowsum16(p[j]);                 // DPP all-reduce over lr
            a_self[j] = b1s + p[j];
            s[j] = 0.f;
#pragma unroll
            for (int ct = 0; ct < 4; ++ct) xsum[ct][j] = 0.f;
        }
        if (w == 0) {
#pragma unroll
            for (int ct = 0; ct < 4; ++ct)
#pragma unroll
                for (int j = 0; j < 4; ++j)
                    xcat[(lg * 4 + j) * 136 + ct * 16 + lr] = (_Float16)xa[ct][j];
        }
    }

    // ---------------- this wave's 3-4 "other" agents: no-max softmax ----------------
    for (int a = abeg; a < aend; ++a) {
        float f0[8] = {q0.x, q0.y, q0.z, q0.w, q1.x, q1.y, q1.z, q1.w};
        float f1[8] = {c0.x, c0.y, c0.z, c0.w, c1.x, c1.y, c1.z, c1.w};
        f16x8 bi0 = cvt8(f0);
        f16x8 bi1 = cvt8(f1);

        if (a + 1 < aend) {   // prefetch next agent
            q0 = *reinterpret_cast<const float4*>(obase + (a + 1) * 32);
            q1 = *reinterpret_cast<const float4*>(obase + (a + 1) * 32 + 4);
            if (lg == 0) {
                c0 = *reinterpret_cast<const float4*>(abase + (a + 1) * 8);
                c1 = *reinterpret_cast<const float4*>(abase + (a + 1) * 8 + 4);
            }
        }

        f32x4 acc[4];
#pragma unroll
        for (int ct = 0; ct < 4; ++ct) {
            acc[ct] = (f32x4){b0c[ct], b0c[ct], b0c[ct], b0c[ct]};  // bias folded
            acc[ct] = MFMA(bi0, w0h[0][ct], acc[ct]);
            acc[ct] = MFMA(bi1, w0h[1][ct], acc[ct]);
        }

        float xa[4][4], p[4];
#pragma unroll
        for (int j = 0; j < 4; ++j) {
#pragma unroll
            for (int ct = 0; ct < 4; ++ct)
                xa[ct][j] = fast_tanh(acc[ct][j]);
            p[j] = xa[0][j] * W1oc[0];
            p[j] = fmaf(xa[1][j], W1oc[1], p[j]);
            p[j] = fmaf(xa[2][j], W1oc[2], p[j]);
            p[j] = fmaf(xa[3][j], W1oc[3], p[j]);
            p[j] = rowsum16(p[j]);                 // DPP all-reduce over lr
        }
        // bounded logits -> softmax without max-subtraction, pure accumulation
#pragma unroll
        for (int j = 0; j < 4; ++j) {
            const float e = __builtin_amdgcn_exp2f(lrelu(a_self[j] + p[j]) * LOG2E);
            s[j] += e;
#pragma unroll
            for (int ct = 0; ct < 4; ++ct)
                xsum[ct][j] = fmaf(e, xa[ct][j], xsum[ct][j]);
        }
    }

    // ---------------- merge waves 1-3 partials into wave0, write x_sum (fp16) ----------------
    if (w >= 1) {
#pragma unroll
        for (int j = 0; j < 4; ++j) {
#pragma unroll
            for (int ct = 0; ct < 4; ++ct)
                part[w - 1][(lg * 4 + j) * 68 + ct * 16 + lr] = xsum[ct][j];
            if (lr == 0) ps[w - 1][lg * 4 + j] = s[j];
        }
    }
    __syncthreads();
    if (w == 0) {
#pragma unroll
        for (int j = 0; j < 4; ++j) {
            const int row = lg * 4 + j;
            const float stot = s[j] + ps[0][row] + ps[1][row] + ps[2][row];
            const float inv = __builtin_amdgcn_rcpf(stot);
#pragma unroll
            for (int ct = 0; ct < 4; ++ct) {
                const int o = row * 68 + ct * 16 + lr;
                const float xs = xsum[ct][j] + part[0][o] + part[1][o] + part[2][o];
                xcat[row * 136 + 64 + ct * 16 + lr] = (_Float16)(xs * inv);
            }
        }
    }
    __syncthreads();

    // ---------------- phase B: wave w owns cols [32w, 32w+32), fp16 A-operand ----------------
    float b2c[2], b3c[2], Wcc[2];
#pragma unroll
    for (int ct = 0; ct < 2; ++ct) {
        const int ctg = w * 2 + ct;
        b2c[ct] = b2[ctg * 16 + lr];
        b3c[ct] = b3[ctg * 16 + lr];
        Wcc[ct] = Wc[ctg * 16 + lr];
    }
    const float bcs = bcv[0];

    f32x4 acc2[2];
#pragma unroll
    for (int ct = 0; ct < 2; ++ct)
        acc2[ct] = (f32x4){b2c[ct], b2c[ct], b2c[ct], b2c[ct]};   // bias folded
#pragma unroll
    for (int ks = 0; ks < 4; ++ks) {
        f16x8 ah = *reinterpret_cast<const f16x8*>(&xcat[lr * 136 + ks * 32 + lg * 8]);
#pragma unroll
        for (int ct = 0; ct < 2; ++ct) {
            const int ctg = w * 2 + ct;
            const long gg = ((long)(ks * 8 + ctg) * 4 + lg) * 16 + lr;
            f16x8 bh = *reinterpret_cast<const f16x8*>(ws + 8192 + gg * 8);
            f16x8 bl = *reinterpret_cast<const f16x8*>(ws + 24576 + gg * 8);
            acc2[ct] = MFMA(ah, bl, acc2[ct]);
            acc2[ct] = MFMA(ah, bh, acc2[ct]);
        }
    }
    __syncthreads();   // all x_cat reads done before x1 overwrite
#pragma unroll
    for (int ct = 0; ct < 2; ++ct)
#pragma unroll
        for (int j = 0; j < 4; ++j)
            xcat[(lg * 4 + j) * 136 + (w * 2 + ct) * 16 + lr] =
                (_Float16)lrelu(acc2[ct][j]);
    __syncthreads();

#pragma unroll
    for (int ct = 0; ct < 2; ++ct)
        acc2[ct] = (f32x4){b3c[ct], b3c[ct], b3c[ct], b3c[ct]};   // bias folded
#pragma unroll
    for (int ks = 0; ks < 4; ++ks) {
        f16x8 ah = *reinterpret_cast<const f16x8*>(&xcat[lr * 136 + ks * 32 + lg * 8]);
#pragma unroll
        for (int ct = 0; ct < 2; ++ct) {
            const int ctg = w * 2 + ct;
            const long gg = ((long)(ks * 8 + ctg) * 4 + lg) * 16 + lr;
            f16x8 bh = *reinterpret_cast<const f16x8*>(ws + 40960 + gg * 8);
            f16x8 bl = *reinterpret_cast<const f16x8*>(ws + 57344 + gg * 8);
            acc2[ct] = MFMA(ah, bl, acc2[ct]);
            acc2[ct] = MFMA(ah, bh, acc2[ct]);
        }
    }

    // value: per-lane partials over this wave's 32 cols, DPP all-reduce over lr
    float v[4];
#pragma unroll
    for (int j = 0; j < 4; ++j) {
        v[j] = lrelu(acc2[0][j]) * Wcc[0];
        v[j] = fmaf(lrelu(acc2[1][j]), Wcc[1], v[j]);
        v[j] = rowsum16(v[j]);
    }
    if (lr == 0) {
#pragma unroll
        for (int j = 0; j < 4; ++j)
            vpart[w][lg * 4 + j] = v[j];
    }
    __syncthreads();
    if (w == 0 && lr == 0) {
#pragma unroll
        for (int j = 0; j < 4; ++j) {
            const int row = lg * 4 + j;
            out[ibase + row] = (vpart[0][row] + vpart[1][row]) +
                               (vpart[2][row] + vpart[3][row]) + bcs;
        }
    }
}

extern "C" void kernel_launch(void* const* d_in, const int* in_sizes, int n_in,
                              void* d_out, int out_size, void* d_ws, size_t ws_size,
                              hipStream_t stream) {
    (void)in_sizes; (void)n_in; (void)ws_size; (void)out_size;
    const float* obs = (const float*)d_in[0];
    const float* act = (const float*)d_in[1];
    const float* W0  = (const float*)d_in[2];
    const float* b0  = (const float*)d_in[3];
    const float* W1  = (const float*)d_in[4];
    const float* b1  = (const float*)d_in[5];
    const float* W2  = (const float*)d_in[6];
    const float* b2  = (const float*)d_in[7];
    const float* W3  = (const float*)d_in[8];
    const float* b3  = (const float*)d_in[9];
    const float* Wc  = (const float*)d_in[10];
    const float* bc  = (const float*)d_in[11];
    _Float16* ws = (_Float16*)d_ws;

    pack_weights<<<dim3(18), dim3(256), 0, stream>>>(W0, W2, W3, ws);
    critic_attention_kernel<<<dim3(65536 / 16), dim3(256), 0, stream>>>(
        obs, act, b0, W1, b1, b2, b3, Wc, bc, ws, (float*)d_out);
}

// Round 22
// 57.858 us; speedup vs baseline: 1.1170x; 1.1170x over previous
//
#include <hip/hip_runtime.h>
#include <math.h>

// critic_attention, round 22: r20 champion (61.0us) + TWO item-tiles per wave.
// r20/r21 evidence: exactly one generation of waves (8/SIMD), per-wave issue
// 5.5k cyc vs 18k lifetime -> 70% dependency stall; more waves can't help
// (r21), only intra-wave ILP can. Fix: each wave processes 2 independent
// 16-item tiles; each agent iteration = body(T0); body(T1) with disjoint
// registers -> compiler interleaves, T0 stalls filled by T1 issue.
// (r15's pairing failed because paired agents shared xsum - serial. Tiles
// share NOTHING until the final merge.)
// Grid 2048 x 128thr; same 2-wave agent-split, no-max softmax, DPP reduces,
// W0-hi-only, HW transcendentals, pkrtz cvt, fp16 xcat - all r20-validated.
//
// Fragment conventions (m89-verified, rounds 6-21):
//   A-frag: lane row (l&15)=item, k=(l>>4)*8+e ; B-frag: lane col, same k
//   D: lane col (l&15), row=(l>>4)*4+reg = item
// ws layout (halfs): W0h@0[2][4][4][16][8] W0l@4096(unused) |
//   W2h@8192[4][8][4][16][8] W2l@24576 | W3h@40960 W3l@57344.

#define SLOPE 0.01f
#define LOG2E 1.4426950408889634f

typedef _Float16 f16x8 __attribute__((ext_vector_type(8)));
typedef _Float16 f16x2 __attribute__((ext_vector_type(2)));
typedef float f32x4 __attribute__((ext_vector_type(4)));

#define MFMA(a, b, c) __builtin_amdgcn_mfma_f32_16x16x32_f16((a), (b), (c), 0, 0, 0)

__device__ __forceinline__ float lrelu(float x) { return fmaxf(x, SLOPE * x); }

// tanh(x) = 1 - 2/(e^{2x}+1), raw v_exp_f32 + v_rcp_f32
__device__ __forceinline__ float fast_tanh(float x) {
    float e = __builtin_amdgcn_exp2f(x * (2.0f * LOG2E));
    float r = __builtin_amdgcn_rcpf(e + 1.0f);
    return fmaf(-2.0f, r, 1.0f);
}

// 8x f32 -> f16x8 via 4x v_cvt_pkrtz_f16_f32 (packed output = MFMA layout)
__device__ __forceinline__ f16x8 cvt8(const float f[8]) {
    f16x2 a = __builtin_bit_cast(f16x2, __builtin_amdgcn_cvt_pkrtz(f[0], f[1]));
    f16x2 b = __builtin_bit_cast(f16x2, __builtin_amdgcn_cvt_pkrtz(f[2], f[3]));
    f16x2 c = __builtin_bit_cast(f16x2, __builtin_amdgcn_cvt_pkrtz(f[4], f[5]));
    f16x2 d = __builtin_bit_cast(f16x2, __builtin_amdgcn_cvt_pkrtz(f[6], f[7]));
    f16x8 r;
    r[0] = a[0]; r[1] = a[1]; r[2] = b[0]; r[3] = b[1];
    r[4] = c[0]; r[5] = c[1]; r[6] = d[0]; r[7] = d[1];
    return r;
}

// all-lanes sum within each 16-lane row: 4x v_add with DPP row_ror (VALU pipe)
__device__ __forceinline__ float rowsum16(float x) {
    int t;
    t = __builtin_amdgcn_update_dpp(0, __builtin_bit_cast(int, x), 0x121, 0xf, 0xf, true);
    x += __builtin_bit_cast(float, t);
    t = __builtin_amdgcn_update_dpp(0, __builtin_bit_cast(int, x), 0x122, 0xf, 0xf, true);
    x += __builtin_bit_cast(float, t);
    t = __builtin_amdgcn_update_dpp(0, __builtin_bit_cast(int, x), 0x124, 0xf, 0xf, true);
    x += __builtin_bit_cast(float, t);
    t = __builtin_amdgcn_update_dpp(0, __builtin_bit_cast(int, x), 0x128, 0xf, 0xf, true);
    x += __builtin_bit_cast(float, t);
    return x;
}

// ---------------- prep: split weights into per-lane fp16 hi/lo fragments ----------------
__global__ __launch_bounds__(256) void pack_weights(
    const float* __restrict__ W0, const float* __restrict__ W2,
    const float* __restrict__ W3, _Float16* __restrict__ ws)
{
    const int g = blockIdx.x * 256 + threadIdx.x;
    if (g >= 4608) return;

    const float* src;
    int ks, ct, lg, lr, ncol, kmax;
    long hoff, loff;
    if (g < 512) {                       // W0: [2][4][4][16]
        ks = g >> 8; ct = (g >> 6) & 3; lg = (g >> 4) & 3; lr = g & 15;
        src = W0; ncol = 64; kmax = 40;
        hoff = (long)g * 8;  loff = hoff + 4096;
    } else if (g < 2560) {               // W2: [4][8][4][16]
        int gg = g - 512;
        ks = gg >> 9; ct = (gg >> 6) & 7; lg = (gg >> 4) & 3; lr = gg & 15;
        src = W2; ncol = 128; kmax = 128;
        hoff = 8192 + (long)gg * 8; loff = hoff + 16384;
    } else {                             // W3: [4][8][4][16]
        int gg = g - 2560;
        ks = gg >> 9; ct = (gg >> 6) & 7; lg = (gg >> 4) & 3; lr = gg & 15;
        src = W3; ncol = 128; kmax = 128;
        hoff = 40960 + (long)gg * 8; loff = hoff + 16384;
    }

    f16x8 hi, lo;
#pragma unroll
    for (int e = 0; e < 8; ++e) {
        const int k = ks * 32 + lg * 8 + e;
        const float v = (k < kmax) ? src[(long)k * ncol + ct * 16 + lr] : 0.f;
        _Float16 h = (_Float16)v;
        hi[e] = h;
        lo[e] = (_Float16)(v - (float)h);
    }
    *reinterpret_cast<f16x8*>(ws + hoff) = hi;
    *reinterpret_cast<f16x8*>(ws + loff) = lo;
}

__global__ __launch_bounds__(128, 2) void critic_attention_kernel(
    const float* __restrict__ obs, const float* __restrict__ act,
    const float* __restrict__ b0, const float* __restrict__ W1,
    const float* __restrict__ b1v, const float* __restrict__ b2,
    const float* __restrict__ b3, const float* __restrict__ Wc,
    const float* __restrict__ bcv, const _Float16* __restrict__ ws,
    float* __restrict__ out)
{
    __shared__ __align__(16) _Float16 xcat[2][16 * 136]; // per-tile x_cat/x1 fp16
    __shared__ float part[2][16 * 68]; // wave1 partial xsum per tile
    __shared__ float ps[2][16];        // wave1 partial s per tile
    __shared__ float vpart[2][2][16];  // [tile][wave][row] Wc partials

    const int t = threadIdx.x;
    const int lane = t & 63;
    const int w = t >> 6;              // wave 0/1
    const int lr = lane & 15;          // A-row (item) / D-col
    const int lg = lane >> 4;          // k-chunk / D-row-group

    const long ibase = (long)blockIdx.x * 32;   // two 16-item tiles

    // W0 HI fragments only
    f16x8 w0h[2][4];
#pragma unroll
    for (int ks = 0; ks < 2; ++ks)
#pragma unroll
        for (int ct = 0; ct < 4; ++ct) {
            const long o = (((long)(ks * 4 + ct) * 4 + lg) * 16 + lr) * 8;
            w0h[ks][ct] = *reinterpret_cast<const f16x8*>(ws + o);
        }

    float b0c[4], W1sc[4], W1oc[4];
#pragma unroll
    for (int ct = 0; ct < 4; ++ct) {
        b0c[ct]  = b0[ct * 16 + lr];
        W1sc[ct] = W1[ct * 16 + lr];
        W1oc[ct] = W1[64 + ct * 16 + lr];
    }
    const float b1s = b1v[0];

    const float* obase[2] = {obs + (ibase + lr) * 512 + lg * 8,
                             obs + (ibase + 16 + lr) * 512 + lg * 8};
    const float* abase[2] = {act + (ibase + lr) * 128,
                             act + (ibase + 16 + lr) * 128};

    const int abeg = w ? 8 : 1;        // wave0: agents 1..7; wave1: agents 8..15
    const int aend = w ? 16 : 8;

    float4 q0[2], q1[2], c0[2], c1[2];
#pragma unroll
    for (int tl = 0; tl < 2; ++tl) {
        q0[tl] = *reinterpret_cast<const float4*>(obase[tl]);
        q1[tl] = *reinterpret_cast<const float4*>(obase[tl] + 4);
        c0[tl] = make_float4(0.f, 0.f, 0.f, 0.f); c1[tl] = c0[tl];
        if (lg == 0) {
            c0[tl] = *reinterpret_cast<const float4*>(abase[tl]);
            c1[tl] = *reinterpret_cast<const float4*>(abase[tl] + 4);
        }
    }

    // ---------------- agent 0 both tiles: a_self (w0 also stores x_self) ----------------
    float a_self[2][4], s[2][4], xsum[2][4][4];
#pragma unroll
    for (int tl = 0; tl < 2; ++tl) {
        float f0[8] = {q0[tl].x, q0[tl].y, q0[tl].z, q0[tl].w,
                       q1[tl].x, q1[tl].y, q1[tl].z, q1[tl].w};
        float f1[8] = {c0[tl].x, c0[tl].y, c0[tl].z, c0[tl].w,
                       c1[tl].x, c1[tl].y, c1[tl].z, c1[tl].w};
        f16x8 bi0 = cvt8(f0);
        f16x8 bi1 = cvt8(f1);

        // prefetch this wave's first loop agent for this tile
        q0[tl] = *reinterpret_cast<const float4*>(obase[tl] + abeg * 32);
        q1[tl] = *reinterpret_cast<const float4*>(obase[tl] + abeg * 32 + 4);
        if (lg == 0) {
            c0[tl] = *reinterpret_cast<const float4*>(abase[tl] + abeg * 8);
            c1[tl] = *reinterpret_cast<const float4*>(abase[tl] + abeg * 8 + 4);
        }

        f32x4 acc[4];
#pragma unroll
        for (int ct = 0; ct < 4; ++ct) {
            acc[ct] = (f32x4){b0c[ct], b0c[ct], b0c[ct], b0c[ct]};
            acc[ct] = MFMA(bi0, w0h[0][ct], acc[ct]);
            acc[ct] = MFMA(bi1, w0h[1][ct], acc[ct]);
        }

        float xa[4][4], p[4];
#pragma unroll
        for (int j = 0; j < 4; ++j) {
#pragma unroll
            for (int ct = 0; ct < 4; ++ct)
                xa[ct][j] = lrelu(acc[ct][j]);
            p[j] = xa[0][j] * W1sc[0];
            p[j] = fmaf(xa[1][j], W1sc[1], p[j]);
            p[j] = fmaf(xa[2][j], W1sc[2], p[j]);
            p[j] = fmaf(xa[3][j], W1sc[3], p[j]);
            p[j] = rowsum16(p[j]);
            a_self[tl][j] = b1s + p[j];
            s[tl][j] = 0.f;
#pragma unroll
            for (int ct = 0; ct < 4; ++ct) xsum[tl][ct][j] = 0.f;
        }
        if (w == 0) {
#pragma unroll
            for (int ct = 0; ct < 4; ++ct)
#pragma unroll
                for (int j = 0; j < 4; ++j)
                    xcat[tl][(lg * 4 + j) * 136 + ct * 16 + lr] = (_Float16)xa[ct][j];
        }
    }

    // ---------------- "other" agents: body(T0); body(T1) per iteration ----------------
    for (int a = abeg; a < aend; ++a) {
#pragma unroll
        for (int tl = 0; tl < 2; ++tl) {
            float f0[8] = {q0[tl].x, q0[tl].y, q0[tl].z, q0[tl].w,
                           q1[tl].x, q1[tl].y, q1[tl].z, q1[tl].w};
            float f1[8] = {c0[tl].x, c0[tl].y, c0[tl].z, c0[tl].w,
                           c1[tl].x, c1[tl].y, c1[tl].z, c1[tl].w};
            f16x8 bi0 = cvt8(f0);
            f16x8 bi1 = cvt8(f1);

            if (a + 1 < aend) {   // prefetch next agent for this tile
                q0[tl] = *reinterpret_cast<const float4*>(obase[tl] + (a + 1) * 32);
                q1[tl] = *reinterpret_cast<const float4*>(obase[tl] + (a + 1) * 32 + 4);
                if (lg == 0) {
                    c0[tl] = *reinterpret_cast<const float4*>(abase[tl] + (a + 1) * 8);
                    c1[tl] = *reinterpret_cast<const float4*>(abase[tl] + (a + 1) * 8 + 4);
                }
            }

            f32x4 acc[4];
#pragma unroll
            for (int ct = 0; ct < 4; ++ct) {
                acc[ct] = (f32x4){b0c[ct], b0c[ct], b0c[ct], b0c[ct]};
                acc[ct] = MFMA(bi0, w0h[0][ct], acc[ct]);
                acc[ct] = MFMA(bi1, w0h[1][ct], acc[ct]);
            }

            float xa[4][4], p[4];
#pragma unroll
            for (int j = 0; j < 4; ++j) {
#pragma unroll
                for (int ct = 0; ct < 4; ++ct)
                    xa[ct][j] = fast_tanh(acc[ct][j]);
                p[j] = xa[0][j] * W1oc[0];
                p[j] = fmaf(xa[1][j], W1oc[1], p[j]);
                p[j] = fmaf(xa[2][j], W1oc[2], p[j]);
                p[j] = fmaf(xa[3][j], W1oc[3], p[j]);
                p[j] = rowsum16(p[j]);
            }
#pragma unroll
            for (int j = 0; j < 4; ++j) {
                const float e = __builtin_amdgcn_exp2f(
                    lrelu(a_self[tl][j] + p[j]) * LOG2E);
                s[tl][j] += e;
#pragma unroll
                for (int ct = 0; ct < 4; ++ct)
                    xsum[tl][ct][j] = fmaf(e, xa[ct][j], xsum[tl][ct][j]);
            }
        }
    }

    // ---------------- merge wave1 partials, write x_sum (fp16) ----------------
    if (w == 1) {
#pragma unroll
        for (int tl = 0; tl < 2; ++tl)
#pragma unroll
            for (int j = 0; j < 4; ++j) {
#pragma unroll
                for (int ct = 0; ct < 4; ++ct)
                    part[tl][(lg * 4 + j) * 68 + ct * 16 + lr] = xsum[tl][ct][j];
                if (lr == 0) ps[tl][lg * 4 + j] = s[tl][j];
            }
    }
    __syncthreads();
    if (w == 0) {
#pragma unroll
        for (int tl = 0; tl < 2; ++tl)
#pragma unroll
            for (int j = 0; j < 4; ++j) {
                const int row = lg * 4 + j;
                const float stot = s[tl][j] + ps[tl][row];
                const float inv = __builtin_amdgcn_rcpf(stot);
#pragma unroll
                for (int ct = 0; ct < 4; ++ct)
                    xcat[tl][row * 136 + 64 + ct * 16 + lr] = (_Float16)(
                        (xsum[tl][ct][j] + part[tl][row * 68 + ct * 16 + lr]) * inv);
            }
    }
    __syncthreads();

    // ---------------- phase B per tile: wave w owns cols [w*64, w*64+64) ----------------
    float b2c[4], b3c[4], Wcc[4];
#pragma unroll
    for (int ct = 0; ct < 4; ++ct) {
        const int ctg = w * 4 + ct;
        b2c[ct] = b2[ctg * 16 + lr];
        b3c[ct] = b3[ctg * 16 + lr];
        Wcc[ct] = Wc[ctg * 16 + lr];
    }
    const float bcs = bcv[0];

    f32x4 acc2[2][4];
#pragma unroll
    for (int tl = 0; tl < 2; ++tl)
#pragma unroll
        for (int ct = 0; ct < 4; ++ct)
            acc2[tl][ct] = (f32x4){b2c[ct], b2c[ct], b2c[ct], b2c[ct]};
#pragma unroll
    for (int ks = 0; ks < 4; ++ks) {
#pragma unroll
        for (int tl = 0; tl < 2; ++tl) {
            f16x8 ah = *reinterpret_cast<const f16x8*>(
                &xcat[tl][lr * 136 + ks * 32 + lg * 8]);
#pragma unroll
            for (int ct = 0; ct < 4; ++ct) {
                const int ctg = w * 4 + ct;
                const long gg = ((long)(ks * 8 + ctg) * 4 + lg) * 16 + lr;
                f16x8 bh = *reinterpret_cast<const f16x8*>(ws + 8192 + gg * 8);
                f16x8 bl = *reinterpret_cast<const f16x8*>(ws + 24576 + gg * 8);
                acc2[tl][ct] = MFMA(ah, bl, acc2[tl][ct]);
                acc2[tl][ct] = MFMA(ah, bh, acc2[tl][ct]);
            }
        }
    }
    __syncthreads();   // all x_cat reads done before x1 overwrite
#pragma unroll
    for (int tl = 0; tl < 2; ++tl)
#pragma unroll
        for (int ct = 0; ct < 4; ++ct)
#pragma unroll
            for (int j = 0; j < 4; ++j)
                xcat[tl][(lg * 4 + j) * 136 + (w * 4 + ct) * 16 + lr] =
                    (_Float16)lrelu(acc2[tl][ct][j]);
    __syncthreads();

#pragma unroll
    for (int tl = 0; tl < 2; ++tl)
#pragma unroll
        for (int ct = 0; ct < 4; ++ct)
            acc2[tl][ct] = (f32x4){b3c[ct], b3c[ct], b3c[ct], b3c[ct]};
#pragma unroll
    for (int ks = 0; ks < 4; ++ks) {
#pragma unroll
        for (int tl = 0; tl < 2; ++tl) {
            f16x8 ah = *reinterpret_cast<const f16x8*>(
                &xcat[tl][lr * 136 + ks * 32 + lg * 8]);
#pragma unroll
            for (int ct = 0; ct < 4; ++ct) {
                const int ctg = w * 4 + ct;
                const long gg = ((long)(ks * 8 + ctg) * 4 + lg) * 16 + lr;
                f16x8 bh = *reinterpret_cast<const f16x8*>(ws + 40960 + gg * 8);
                f16x8 bl = *reinterpret_cast<const f16x8*>(ws + 57344 + gg * 8);
                acc2[tl][ct] = MFMA(ah, bl, acc2[tl][ct]);
                acc2[tl][ct] = MFMA(ah, bh, acc2[tl][ct]);
            }
        }
    }

    // value: per-lane partials, DPP all-reduce over lr, per tile
#pragma unroll
    for (int tl = 0; tl < 2; ++tl) {
        float v[4];
#pragma unroll
        for (int j = 0; j < 4; ++j) {
            v[j] = lrelu(acc2[tl][0][j]) * Wcc[0];
#pragma unroll
            for (int ct = 1; ct < 4; ++ct)
                v[j] = fmaf(lrelu(acc2[tl][ct][j]), Wcc[ct], v[j]);
            v[j] = rowsum16(v[j]);
        }
        if (lr == 0) {
#pragma unroll
            for (int j = 0; j < 4; ++j)
                vpart[tl][w][lg * 4 + j] = v[j];
        }
    }
    __syncthreads();
    if (w == 0 && lr == 0) {
#pragma unroll
        for (int tl = 0; tl < 2; ++tl)
#pragma unroll
            for (int j = 0; j < 4; ++j) {
                const int row = lg * 4 + j;
                out[ibase + tl * 16 + row] =
                    vpart[tl][0][row] + vpart[tl][1][row] + bcs;
            }
    }
}

extern "C" void kernel_launch(void* const* d_in, const int* in_sizes, int n_in,
                              void* d_out, int out_size, void* d_ws, size_t ws_size,
                              hipStream_t stream) {
    (void)in_sizes; (void)n_in; (void)ws_size; (void)out_size;
    const float* obs = (const float*)d_in[0];
    const float* act = (const float*)d_in[1];
    const float* W0  = (const float*)d_in[2];
    const float* b0  = (const float*)d_in[3];
    const float* W1  = (const float*)d_in[4];
    const float* b1  = (const float*)d_in[5];
    const float* W2  = (const float*)d_in[6];
    const float* b2  = (const float*)d_in[7];
    const float* W3  = (const float*)d_in[8];
    const float* b3  = (const float*)d_in[9];
    const float* Wc  = (const float*)d_in[10];
    const float* bc  = (const float*)d_in[11];
    _Float16* ws = (_Float16*)d_ws;

    pack_weights<<<dim3(18), dim3(256), 0, stream>>>(W0, W2, W3, ws);
    critic_attention_kernel<<<dim3(65536 / 32), dim3(128), 0, stream>>>(
        obs, act, b0, W1, b1, b2, b3, Wc, bc, ws, (float*)d_out);
}